// Round 1
// baseline (166.719 us; speedup 1.0000x reference)
//
#include <hip/hip_runtime.h>
#include <hip/hip_bf16.h>

// 2-bit quantized embedding gather.
// VOCAB=400000, DIM=128, NBITS=2 -> each token owns exactly 8 int32 words
// (256 bits), word-aligned: token t's codes are bit_arr[8t .. 8t+7].
// Decode: dim d of token t -> word 8t + d/16, shift (d%16)*2, code = 2 bits,
// out = codebook[code].
//
// Mapping: 32 threads per token, 4 dims (one float4) per thread.
// Thread k: word = 8t + (k>>2), byte (k&3) of that word holds its 4 codes.
// Consecutive lanes store consecutive float4 -> fully coalesced 16B/lane.

#define EMB_DIM 128

__global__ __launch_bounds__(256) void embed2bit_kernel(
    const int* __restrict__ ids,      // [n_tokens] int32
    const int* __restrict__ bits,     // [3,200,000] packed int32
    const float* __restrict__ cb,     // [4] codebook
    float* __restrict__ out,          // [n_tokens, 128] fp32
    int n_tokens)
{
    int gid = blockIdx.x * blockDim.x + threadIdx.x;
    int t = gid >> 5;          // token index (32 threads/token)
    int k = gid & 31;          // which float4 within the token's 128 dims
    if (t >= n_tokens) return;

    int tok = ids[t];                         // broadcast within 32 lanes
    int word = bits[tok * 8 + (k >> 2)];      // 4 lanes share a word
    int byte = (word >> ((k & 3) * 8)) & 0xff;

    float c0 = cb[0], c1 = cb[1], c2 = cb[2], c3 = cb[3];

    float4 r;
    float* rp = &r.x;
#pragma unroll
    for (int j = 0; j < 4; ++j) {
        int c = (byte >> (2 * j)) & 3;
        float lo = (c & 1) ? c1 : c0;
        float hi = (c & 1) ? c3 : c2;
        rp[j] = (c & 2) ? hi : lo;            // 2x v_cndmask per element
    }

    *reinterpret_cast<float4*>(out + (size_t)t * EMB_DIM + k * 4) = r;
}

extern "C" void kernel_launch(void* const* d_in, const int* in_sizes, int n_in,
                              void* d_out, int out_size, void* d_ws, size_t ws_size,
                              hipStream_t stream) {
    const int*   ids  = (const int*)d_in[0];
    const int*   bits = (const int*)d_in[1];
    const float* cb   = (const float*)d_in[2];
    float*       out  = (float*)d_out;

    int n_tokens = in_sizes[0];               // 262,144
    long long total_threads = (long long)n_tokens * 32;
    int block = 256;
    int grid = (int)((total_threads + block - 1) / block);

    embed2bit_kernel<<<grid, block, 0, stream>>>(ids, bits, cb, out, n_tokens);
}

// Round 3
// 163.752 us; speedup vs baseline: 1.0181x; 1.0181x over previous
//
#include <hip/hip_runtime.h>
#include <hip/hip_bf16.h>

// 2-bit quantized embedding gather.
// VOCAB=400000, DIM=128, NBITS=2 -> token t owns exactly 8 aligned int32
// words: bit_arr[8t .. 8t+7]. dim d -> word 8t + d/16, code = 2 bits.
//
// Work item i (of n_tokens*32): token t = i>>5, float4 slot k = i&31.
// Thread k of a token reads word 8t + (k>>2), byte (k&3), decodes 4 codes,
// stores one float4. Consecutive items -> consecutive 16B stores (coalesced).
//
// R2/R3: 4 items in flight per thread (batched loads) to break the
// serialized ids->bits->store dependent chain (latency-bound at ~75us with
// 1 item/thread). Nontemporal stores keep the 128MiB output stream from
// evicting the 12.8MiB bit_arr in L2.
// R3 fix: __builtin_nontemporal_store needs a clang ext_vector_type, not
// HIP's float4 class -> use vfloat4.

#define EMB_DIM 128

typedef float vfloat4 __attribute__((ext_vector_type(4)));

__global__ __launch_bounds__(256, 8) void embed2bit_kernel(
    const int* __restrict__ ids,      // [n_tokens] int32
    const int* __restrict__ bits,     // [3,200,000] packed int32
    const float* __restrict__ cb,     // [4] codebook
    float* __restrict__ out,          // [n_tokens, 128] fp32
    int n_tokens)
{
    const long long n_items = (long long)n_tokens * 32;
    const long long stride  = (long long)gridDim.x * blockDim.x;
    long long gid = (long long)blockIdx.x * blockDim.x + threadIdx.x;

    float c0 = cb[0], c1 = cb[1], c2 = cb[2], c3 = cb[3];

    for (long long base = gid; base < n_items; base += 4 * stride) {
        long long idx[4];
        int tok[4], wrd[4];
        bool ok[4];

        // Phase 1: 4 independent ids loads in flight
#pragma unroll
        for (int j = 0; j < 4; ++j) {
            idx[j] = base + (long long)j * stride;
            ok[j]  = idx[j] < n_items;
            tok[j] = ok[j] ? ids[idx[j] >> 5] : 0;
        }
        // Phase 2: 4 independent bits loads in flight
#pragma unroll
        for (int j = 0; j < 4; ++j) {
            int k  = (int)(idx[j] & 31);
            wrd[j] = ok[j] ? bits[(long long)tok[j] * 8 + (k >> 2)] : 0;
        }
        // Phase 3: decode + coalesced nontemporal float4 stores
#pragma unroll
        for (int j = 0; j < 4; ++j) {
            if (!ok[j]) continue;
            int k    = (int)(idx[j] & 31);
            int byte = (wrd[j] >> ((k & 3) * 8)) & 0xff;
            vfloat4 r;
#pragma unroll
            for (int q = 0; q < 4; ++q) {
                int c    = (byte >> (2 * q)) & 3;
                float lo = (c & 1) ? c1 : c0;
                float hi = (c & 1) ? c3 : c2;
                r[q]     = (c & 2) ? hi : lo;   // 2x v_cndmask per element
            }
            long long t = idx[j] >> 5;
            __builtin_nontemporal_store(
                r, reinterpret_cast<vfloat4*>(out + t * EMB_DIM + k * 4));
        }
    }
}

extern "C" void kernel_launch(void* const* d_in, const int* in_sizes, int n_in,
                              void* d_out, int out_size, void* d_ws, size_t ws_size,
                              hipStream_t stream) {
    const int*   ids  = (const int*)d_in[0];
    const int*   bits = (const int*)d_in[1];
    const float* cb   = (const float*)d_in[2];
    float*       out  = (float*)d_out;

    int n_tokens = in_sizes[0];               // 262,144
    long long n_items = (long long)n_tokens * 32;

    int block = 256;
    // 2048 blocks (8 per CU) x 256 threads x 4-item batches covers
    // 8,388,608 items in exactly 4 full loop iterations.
    long long want = (n_items + block - 1) / block;
    int grid = (int)(want < 2048 ? want : 2048);

    embed2bit_kernel<<<grid, block, 0, stream>>>(ids, bits, cb, out, n_tokens);
}

// Round 4
// 152.540 us; speedup vs baseline: 1.0930x; 1.0735x over previous
//
#include <hip/hip_runtime.h>
#include <hip/hip_bf16.h>

// 2-bit quantized embedding gather, split into two streaming kernels.
// VOCAB=400000, DIM=128, NBITS=2 -> token t owns 8 aligned int32 words
// bit_arr[8t..8t+7]; dim d -> word 8t + d/16, 2-bit code, out=codebook[code].
//
// R4: split the two-hop dependent gather (ids -> bits) out of the hot
// 134MB-store kernel. Kernel A streams the gathered words into ws in output
// order (8.4MB, latency-tolerant: 2.1M independent threads). Kernel B is a
// pure linear stream: ws[i>>2] -> decode -> coalesced float4 store at out+4i.
// R1(1 item/thread)==R3(4-deep batch,nt) at ~164us ruled out MLP depth,
// store policy, grid shape; this tests the gather-chain axis.

#define EMB_DIM 128

// --- Kernel A: gather packed words into output order ---------------------
__global__ __launch_bounds__(256) void gather_words_kernel(
    const int* __restrict__ ids,      // [n_tokens]
    const int* __restrict__ bits,     // [3,200,000]
    int* __restrict__ ws_words,       // [n_tokens*8]
    int n_words)                      // n_tokens*8
{
    int i = blockIdx.x * blockDim.x + threadIdx.x;
    if (i >= n_words) return;
    int tok = ids[i >> 3];                    // 8 lanes share one id
    ws_words[i] = bits[tok * 8 + (i & 7)];    // 32B/token random read,
                                              // fully coalesced 1KiB/wave write
}

// --- Kernel B: pure linear decode + store --------------------------------
__global__ __launch_bounds__(256) void decode_kernel(
    const int* __restrict__ ws_words, // [n_tokens*8], already in output order
    const float* __restrict__ cb,     // [4]
    float* __restrict__ out,          // [n_tokens*128] fp32
    int n_items)                      // n_tokens*32 (one float4 per item)
{
    int i = blockIdx.x * blockDim.x + threadIdx.x;
    if (i >= n_items) return;

    int word = ws_words[i >> 2];              // linear: 4 lanes share a word
    int byte = (word >> ((i & 3) * 8)) & 0xff;

    float c0 = cb[0], c1 = cb[1], c2 = cb[2], c3 = cb[3];

    float4 r;
    float* rp = &r.x;
#pragma unroll
    for (int q = 0; q < 4; ++q) {
        int c    = (byte >> (2 * q)) & 3;
        float lo = (c & 1) ? c1 : c0;
        float hi = (c & 1) ? c3 : c2;
        rp[q]    = (c & 2) ? hi : lo;         // 2x v_cndmask per element
    }
    // out offset = t*128 + k*4 = i*4 floats: consecutive lanes ->
    // contiguous 1KiB per wave store.
    *reinterpret_cast<float4*>(out + (size_t)i * 4) = r;
}

// --- Fallback fused kernel (only if ws too small) ------------------------
__global__ __launch_bounds__(256) void fused_kernel(
    const int* __restrict__ ids, const int* __restrict__ bits,
    const float* __restrict__ cb, float* __restrict__ out, int n_items)
{
    int i = blockIdx.x * blockDim.x + threadIdx.x;
    if (i >= n_items) return;
    int t = i >> 5, k = i & 31;
    int tok  = ids[t];
    int word = bits[tok * 8 + (k >> 2)];
    int byte = (word >> ((k & 3) * 8)) & 0xff;
    float c0 = cb[0], c1 = cb[1], c2 = cb[2], c3 = cb[3];
    float4 r; float* rp = &r.x;
#pragma unroll
    for (int q = 0; q < 4; ++q) {
        int c = (byte >> (2 * q)) & 3;
        float lo = (c & 1) ? c1 : c0;
        float hi = (c & 1) ? c3 : c2;
        rp[q] = (c & 2) ? hi : lo;
    }
    *reinterpret_cast<float4*>(out + (size_t)i * 4) = r;
}

extern "C" void kernel_launch(void* const* d_in, const int* in_sizes, int n_in,
                              void* d_out, int out_size, void* d_ws, size_t ws_size,
                              hipStream_t stream) {
    const int*   ids  = (const int*)d_in[0];
    const int*   bits = (const int*)d_in[1];
    const float* cb   = (const float*)d_in[2];
    float*       out  = (float*)d_out;

    int n_tokens = in_sizes[0];               // 262,144
    int n_words  = n_tokens * 8;              // 2,097,152
    int n_items  = n_tokens * 32;             // 8,388,608
    int block = 256;

    if (ws_size >= (size_t)n_words * sizeof(int)) {
        int* ws_words = (int*)d_ws;
        gather_words_kernel<<<(n_words + block - 1) / block, block, 0, stream>>>(
            ids, bits, ws_words, n_words);
        decode_kernel<<<(n_items + block - 1) / block, block, 0, stream>>>(
            ws_words, cb, out, n_items);
    } else {
        fused_kernel<<<(n_items + block - 1) / block, block, 0, stream>>>(
            ids, bits, cb, out, n_items);
    }
}